// Round 6
// baseline (525.690 us; speedup 1.0000x reference)
//
#include <hip/hip_runtime.h>

// MaxUnpooling2D scatter-add via LDS-local multisplit binning, SEGMENTED so
// the record array stays L3-resident between bin and accum phases.
// updates [8,256,256,64] f32, mask int32 (flat index into [512*512*64] plane).
// out [8,512,512,64] f32, duplicates sum.
//
// dest flat (within batch plane) = (m & ~63) | c, c = element's own channel.
// bucket (global) = batch*1024 + (m>>14): 256 output pixels = 64 KB region.
// local idx in bucket = (m & 0x3FC0) | c, 14 bits.

static constexpr int PER_B   = 1 << 22;            // 4,194,304 elems/batch
static constexpr int NB      = 8;
static constexpr int N_ELEM  = NB * PER_B;         // 33,554,432
static constexpr int BPB     = 1024;               // buckets per batch
static constexpr int NBUCK   = NB * BPB;           // 8192
static constexpr int CAP     = 4600;               // mean 4096 + ~8 sigma
static constexpr int TILE    = 8192;               // elements per workgroup
static constexpr int BS      = 1024;               // threads per workgroup (16 waves)
static constexpr int SEG_B   = 2;                  // batches per segment (records 67 MB -> L3)
static constexpr size_t CUR_BYTES = (size_t)NBUCK * 64;        // 1 cursor per 64B line
static constexpr size_t REC_BYTES = (size_t)NBUCK * CAP * 8;   // 301.5 MB

typedef int      i4v __attribute__((ext_vector_type(4)));
typedef float    f4v __attribute__((ext_vector_type(4)));
typedef unsigned u2v __attribute__((ext_vector_type(2)));

// ---- Phase 1: zero cursor lines (512 KB) ----------------------------------
__global__ __launch_bounds__(256)
void zero_cur(uint4* __restrict__ cur) {
    cur[blockIdx.x * 256 + threadIdx.x] = make_uint4(0u, 0u, 0u, 0u);
}

// ---- Phase 2: LDS multisplit -> per-bucket contiguous record runs ---------
// 1024 threads, 8 elems/thread. LDS ~76 KB -> 2 WG/CU = 32 waves/CU.
__global__ __launch_bounds__(BS)
void bin8k(const float* __restrict__ upd,
           const int*  __restrict__ mask,
           unsigned*   __restrict__ cur,
           u2v*        __restrict__ rec,
           int b0) {
    __shared__ unsigned cnt[BPB];      // 4 KB
    __shared__ unsigned pfx[BPB];      // 4 KB exclusive prefix
    __shared__ int      bm[BPB];       // 4 KB  rec_base - pfx
    __shared__ unsigned wsum[16];      // wave partial sums
    __shared__ u2v      srec[TILE];    // 64 KB locally-sorted records

    const int t = threadIdx.x;
    const int tile0 = b0 * PER_B + blockIdx.x * TILE;   // tile fully inside one batch
    const unsigned bb = (unsigned)(tile0 >> 22) << 10;  // global bucket base

    cnt[t] = 0;                                     // BPB == BS
    __syncthreads();

    // histogram with returned rank (mask kept in registers); NT loads (streamed once)
    i4v m4[2];
    unsigned rk[8];
    const int vbase = (tile0 >> 2) + t;             // vec4 index, coalesced per j
    const i4v* mp = reinterpret_cast<const i4v*>(mask);
    #pragma unroll
    for (int j = 0; j < 2; ++j)
        m4[j] = __builtin_nontemporal_load(&mp[vbase + BS * j]);
    #pragma unroll
    for (int j = 0; j < 2; ++j) {
        #pragma unroll
        for (int q = 0; q < 4; ++q) {
            unsigned lb = ((unsigned)m4[j][q] >> 14) & 1023u;
            rk[4 * j + q] = atomicAdd(&cnt[lb], 1u);
        }
    }
    __syncthreads();

    // exclusive scan over cnt[1024]: wave64 shfl scan + cross-wave scan
    const int lane = t & 63, wid = t >> 6;
    unsigned v = cnt[t], x = v;
    #pragma unroll
    for (int off = 1; off < 64; off <<= 1) {
        unsigned y = __shfl_up(x, off, 64);
        if (lane >= off) x += y;
    }
    if (lane == 63) wsum[wid] = x;                  // wave totals
    __syncthreads();
    if (t < 16) {
        unsigned w = wsum[t];
        #pragma unroll
        for (int off = 1; off < 16; off <<= 1) {
            unsigned y = __shfl_up(w, off, 64);
            if (t >= off) w += y;
        }
        wsum[t] = w;                                // inclusive wave-prefix
    }
    __syncthreads();
    unsigned excl = x - v + (wid ? wsum[wid - 1] : 0u);
    pfx[t] = excl;

    // reservation: one bucket per thread, ONE returning atomic per nonempty bucket
    {
        unsigned n = cnt[t];
        unsigned gb = bb + (unsigned)t;
        unsigned pos = 0;
        if (n) pos = atomicAdd(&cur[(size_t)gb * 16], n);
        bm[t] = (int)(gb * (unsigned)CAP + pos) - (int)excl;
    }
    __syncthreads();

    // place records into srec in bucket-major order
    const f4v* up = reinterpret_cast<const f4v*>(upd);
    #pragma unroll
    for (int j = 0; j < 2; ++j) {
        f4v u = __builtin_nontemporal_load(&up[vbase + BS * j]);
        int cbase = (4 * (t + BS * j)) & 63;        // channel of elem q=0
        #pragma unroll
        for (int q = 0; q < 4; ++q) {
            unsigned mm   = (unsigned)m4[j][q];
            float    val  = u[q];
            unsigned lb   = (mm >> 14) & 1023u;
            unsigned lidx = (mm & 0x3FC0u) | (unsigned)(cbase + q);
            unsigned pos  = pfx[lb] + rk[4 * j + q];
            u2v e; e[0] = lidx | (lb << 14); e[1] = __float_as_uint(val);
            srec[pos] = e;
        }
    }
    __syncthreads();

    // copy out: consecutive k in same bucket -> consecutive global addresses.
    // Plain (cached) stores: records must stay L3-resident for bucket_accum.
    #pragma unroll
    for (int j = 0; j < 8; ++j) {
        int k = t + BS * j;
        u2v e = srec[k];
        unsigned lb = e[0] >> 14;
        int dst = bm[lb] + k;
        unsigned end = (bb + lb + 1u) * (unsigned)CAP;   // overflow guard
        if ((unsigned)dst < end) {
            u2v o; o[0] = e[0] & 16383u; o[1] = e[1];
            rec[dst] = o;
        }
    }
}

// ---- Phase 3: per-bucket LDS accumulate + dense nontemporal write ---------
// 1024 threads, 64 KB LDS -> 2 WG/CU = 32 waves/CU.
__global__ __launch_bounds__(BS)
void bucket_accum(const u2v*      __restrict__ rec,
                  const unsigned* __restrict__ cur,
                  float*          __restrict__ out,
                  int b0) {
    __shared__ float lds[16384];       // 64 KB = 256 pixels x 64 C
    int bucket = (b0 << 10) + blockIdx.x;
    int t = threadIdx.x;

    f4v* lds4 = reinterpret_cast<f4v*>(lds);
    f4v z = {0.f, 0.f, 0.f, 0.f};
    #pragma unroll
    for (int k = 0; k < 4; ++k)
        lds4[t + BS * k] = z;
    __syncthreads();

    unsigned n = cur[(size_t)bucket * 16];
    if (n > (unsigned)CAP) n = CAP;
    const u2v* r = rec + (size_t)bucket * CAP;
    for (unsigned k = t; k < n; k += BS) {
        u2v e = __builtin_nontemporal_load(&r[k]);   // read once, don't re-cache
        atomicAdd(&lds[e[0] & 16383u], __uint_as_float(e[1]));
    }
    __syncthreads();

    size_t obase = ((size_t)(bucket >> 10) << 24)     // batch plane
                 + ((size_t)(bucket & 1023) << 14);   // 256-pixel block
    f4v* out4 = reinterpret_cast<f4v*>(out + obase);
    #pragma unroll
    for (int k = 0; k < 4; ++k)
        __builtin_nontemporal_store(lds4[t + BS * k], &out4[t + BS * k]);
}

// ---- Fallback: direct atomic scatter (round-1) ----------------------------
__global__ void unpool_scatter(const float* __restrict__ upd,
                               const int*  __restrict__ mask,
                               float*      __restrict__ out) {
    int i = blockIdx.x * blockDim.x + threadIdx.x;
    int base = i << 2;
    if (base >= N_ELEM) return;
    const int4   m = reinterpret_cast<const int4*>(mask)[i];
    const float4 u = reinterpret_cast<const float4*>(upd)[i];
    int b = base >> 22;
    int c = base & 63;
    size_t obase = ((size_t)b << 24) + c;
    atomicAdd(&out[obase + (size_t)(m.x & ~63)    ], u.x);
    atomicAdd(&out[obase + (size_t)(m.y & ~63) + 1], u.y);
    atomicAdd(&out[obase + (size_t)(m.z & ~63) + 2], u.z);
    atomicAdd(&out[obase + (size_t)(m.w & ~63) + 3], u.w);
}

extern "C" void kernel_launch(void* const* d_in, const int* in_sizes, int n_in,
                              void* d_out, int out_size, void* d_ws, size_t ws_size,
                              hipStream_t stream) {
    const float* upd  = (const float*)d_in[0];
    const int*   mask = (const int*)d_in[1];
    float*       out  = (float*)d_out;

    if (ws_size < CUR_BYTES + REC_BYTES) {
        hipMemsetAsync(out, 0, (size_t)out_size * sizeof(float), stream);
        int n4 = N_ELEM / 4;
        unpool_scatter<<<(n4 + 255) / 256, 256, 0, stream>>>(upd, mask, out);
        return;
    }

    unsigned* cur = (unsigned*)d_ws;
    u2v*      rec = (u2v*)((char*)d_ws + CUR_BYTES);

    zero_cur<<<CUR_BYTES / (256 * 16), 256, 0, stream>>>((uint4*)cur);
    // Segment by batch pairs: each segment's 67 MB of records stays L3-resident
    // between its bin and accum dispatches (record traffic never hits HBM).
    for (int b0 = 0; b0 < NB; b0 += SEG_B) {
        bin8k<<<SEG_B * (PER_B / TILE), BS, 0, stream>>>(upd, mask, cur, rec, b0);
        bucket_accum<<<SEG_B * BPB, BS, 0, stream>>>(rec, cur, out, b0);
    }
}

// Round 7
// 366.734 us; speedup vs baseline: 1.4334x; 1.4334x over previous
//
#include <hip/hip_runtime.h>

// MaxUnpooling2D scatter-add via LDS-local multisplit binning (unsegmented —
// round-6 segmentation regressed; records are L3-resident anyway).
// updates [8,256,256,64] f32, mask int32 (flat index into [512*512*64] plane).
// out [8,512,512,64] f32, duplicates sum.
//
// dest flat (within batch plane) = (m & ~63) | c, c = element's own channel.
// bucket (global) = batch*1024 + (m>>14): 256 output pixels = 64 KB region.
// local idx in bucket = (m & 0x3FC0) | c, 14 bits.
//
// bin16k: TILE=16384 via 128 KB dynamic LDS (gfx950 has 160 KB/CU) -> half the
// reservation atomics, double the copy-out run length vs TILE=8192.

static constexpr int PER_B   = 1 << 22;            // 4,194,304 elems/batch
static constexpr int NB      = 8;
static constexpr int N_ELEM  = NB * PER_B;         // 33,554,432
static constexpr int BPB     = 1024;               // buckets per batch
static constexpr int NBUCK   = NB * BPB;           // 8192
static constexpr int CAP     = 4600;               // mean 4096 + ~8 sigma
static constexpr int TILE    = 16384;              // elements per workgroup
static constexpr int EPT     = TILE / 4 / 1024;    // 4 vec4 loads per thread
static constexpr int BS      = 1024;               // threads per workgroup (16 waves)
static constexpr size_t CUR_BYTES = (size_t)NBUCK * 64;        // 1 cursor per 64B line
static constexpr size_t REC_BYTES = (size_t)NBUCK * CAP * 8;   // 301.5 MB
static constexpr size_t SREC_BYTES = (size_t)TILE * 8;         // 128 KB dynamic LDS

typedef int      i4v __attribute__((ext_vector_type(4)));
typedef float    f4v __attribute__((ext_vector_type(4)));
typedef unsigned u2v __attribute__((ext_vector_type(2)));

// ---- Phase 1: zero cursor lines (512 KB) ----------------------------------
__global__ __launch_bounds__(256)
void zero_cur(uint4* __restrict__ cur) {
    cur[blockIdx.x * 256 + threadIdx.x] = make_uint4(0u, 0u, 0u, 0u);
}

// ---- Phase 2: LDS multisplit -> per-bucket contiguous record runs ---------
// 1024 threads, 16 elems/thread, 128 KB dynamic srec -> 1 WG/CU, 16 waves.
__global__ __launch_bounds__(BS)
void bin16k(const float* __restrict__ upd,
            const int*  __restrict__ mask,
            unsigned*   __restrict__ cur,
            u2v*        __restrict__ rec) {
    __shared__ unsigned cnt[BPB];      // 4 KB
    __shared__ unsigned pfx[BPB];      // 4 KB exclusive prefix
    __shared__ int      bm[BPB];       // 4 KB  rec_base - pfx
    __shared__ unsigned wsum[16];      // wave partial sums
    extern __shared__ u2v srec[];      // 128 KB locally-sorted records

    const int t = threadIdx.x;
    const int tile0 = blockIdx.x * TILE;            // tile fully inside one batch
    const unsigned bb = (unsigned)(tile0 >> 22) << 10;  // global bucket base

    cnt[t] = 0;                                     // BPB == BS
    __syncthreads();

    // histogram with returned rank (mask kept in registers); NT loads
    i4v m4[EPT];
    unsigned rk[4 * EPT];
    const int vbase = (tile0 >> 2) + t;             // vec4 index, coalesced per j
    const i4v* mp = reinterpret_cast<const i4v*>(mask);
    #pragma unroll
    for (int j = 0; j < EPT; ++j)
        m4[j] = __builtin_nontemporal_load(&mp[vbase + BS * j]);
    #pragma unroll
    for (int j = 0; j < EPT; ++j) {
        #pragma unroll
        for (int q = 0; q < 4; ++q) {
            unsigned lb = ((unsigned)m4[j][q] >> 14) & 1023u;
            rk[4 * j + q] = atomicAdd(&cnt[lb], 1u);
        }
    }
    __syncthreads();

    // exclusive scan over cnt[1024]: wave64 shfl scan + cross-wave scan
    const int lane = t & 63, wid = t >> 6;
    unsigned v = cnt[t], x = v;
    #pragma unroll
    for (int off = 1; off < 64; off <<= 1) {
        unsigned y = __shfl_up(x, off, 64);
        if (lane >= off) x += y;
    }
    if (lane == 63) wsum[wid] = x;                  // wave totals
    __syncthreads();
    if (t < 16) {
        unsigned w = wsum[t];
        #pragma unroll
        for (int off = 1; off < 16; off <<= 1) {
            unsigned y = __shfl_up(w, off, 64);
            if (t >= off) w += y;
        }
        wsum[t] = w;                                // inclusive wave-prefix
    }
    __syncthreads();
    unsigned excl = x - v + (wid ? wsum[wid - 1] : 0u);
    pfx[t] = excl;

    // reservation: one bucket per thread, ONE returning atomic per nonempty bucket
    {
        unsigned n = cnt[t];
        unsigned gb = bb + (unsigned)t;
        unsigned pos = 0;
        if (n) pos = atomicAdd(&cur[(size_t)gb * 16], n);
        bm[t] = (int)(gb * (unsigned)CAP + pos) - (int)excl;
    }
    __syncthreads();

    // place records into srec in bucket-major order
    const f4v* up = reinterpret_cast<const f4v*>(upd);
    #pragma unroll
    for (int j = 0; j < EPT; ++j) {
        f4v u = __builtin_nontemporal_load(&up[vbase + BS * j]);
        int cbase = (4 * (t + BS * j)) & 63;        // channel of elem q=0
        #pragma unroll
        for (int q = 0; q < 4; ++q) {
            unsigned mm   = (unsigned)m4[j][q];
            unsigned lb   = (mm >> 14) & 1023u;
            unsigned lidx = (mm & 0x3FC0u) | (unsigned)(cbase + q);
            unsigned pos  = pfx[lb] + rk[4 * j + q];
            u2v e; e[0] = lidx | (lb << 14); e[1] = __float_as_uint(u[q]);
            srec[pos] = e;
        }
    }
    __syncthreads();

    // copy out: consecutive k in same bucket -> consecutive global addresses
    #pragma unroll
    for (int j = 0; j < 4 * EPT; ++j) {
        int k = t + BS * j;
        u2v e = srec[k];
        unsigned lb = e[0] >> 14;
        int dst = bm[lb] + k;
        unsigned end = (bb + lb + 1u) * (unsigned)CAP;   // overflow guard
        if ((unsigned)dst < end) {
            u2v o; o[0] = e[0] & 16383u; o[1] = e[1];
            rec[dst] = o;
        }
    }
}

// ---- Phase 3: per-bucket LDS accumulate + dense nontemporal write ---------
// 1024 threads, 64 KB LDS -> 2 WG/CU = 32 waves/CU.
__global__ __launch_bounds__(BS)
void bucket_accum(const u2v*      __restrict__ rec,
                  const unsigned* __restrict__ cur,
                  float*          __restrict__ out) {
    __shared__ float lds[16384];       // 64 KB = 256 pixels x 64 C
    int bucket = blockIdx.x;
    int t = threadIdx.x;

    f4v* lds4 = reinterpret_cast<f4v*>(lds);
    f4v z = {0.f, 0.f, 0.f, 0.f};
    #pragma unroll
    for (int k = 0; k < 4; ++k)
        lds4[t + BS * k] = z;
    __syncthreads();

    unsigned n = cur[(size_t)bucket * 16];
    if (n > (unsigned)CAP) n = CAP;
    const u2v* r = rec + (size_t)bucket * CAP;
    for (unsigned k = t; k < n; k += BS) {
        u2v e = __builtin_nontemporal_load(&r[k]);   // read once, don't re-cache
        atomicAdd(&lds[e[0] & 16383u], __uint_as_float(e[1]));
    }
    __syncthreads();

    size_t obase = ((size_t)(bucket >> 10) << 24)     // batch plane
                 + ((size_t)(bucket & 1023) << 14);   // 256-pixel block
    f4v* out4 = reinterpret_cast<f4v*>(out + obase);
    #pragma unroll
    for (int k = 0; k < 4; ++k)
        __builtin_nontemporal_store(lds4[t + BS * k], &out4[t + BS * k]);
}

// ---- Fallback: direct atomic scatter (round-1) ----------------------------
__global__ void unpool_scatter(const float* __restrict__ upd,
                               const int*  __restrict__ mask,
                               float*      __restrict__ out) {
    int i = blockIdx.x * blockDim.x + threadIdx.x;
    int base = i << 2;
    if (base >= N_ELEM) return;
    const int4   m = reinterpret_cast<const int4*>(mask)[i];
    const float4 u = reinterpret_cast<const float4*>(upd)[i];
    int b = base >> 22;
    int c = base & 63;
    size_t obase = ((size_t)b << 24) + c;
    atomicAdd(&out[obase + (size_t)(m.x & ~63)    ], u.x);
    atomicAdd(&out[obase + (size_t)(m.y & ~63) + 1], u.y);
    atomicAdd(&out[obase + (size_t)(m.z & ~63) + 2], u.z);
    atomicAdd(&out[obase + (size_t)(m.w & ~63) + 3], u.w);
}

extern "C" void kernel_launch(void* const* d_in, const int* in_sizes, int n_in,
                              void* d_out, int out_size, void* d_ws, size_t ws_size,
                              hipStream_t stream) {
    const float* upd  = (const float*)d_in[0];
    const int*   mask = (const int*)d_in[1];
    float*       out  = (float*)d_out;

    if (ws_size < CUR_BYTES + REC_BYTES) {
        hipMemsetAsync(out, 0, (size_t)out_size * sizeof(float), stream);
        int n4 = N_ELEM / 4;
        unpool_scatter<<<(n4 + 255) / 256, 256, 0, stream>>>(upd, mask, out);
        return;
    }

    unsigned* cur = (unsigned*)d_ws;
    u2v*      rec = (u2v*)((char*)d_ws + CUR_BYTES);

    // Opt in to >64 KB dynamic LDS (gfx950: 160 KB/CU). Non-stream call,
    // graph-capture-safe; deterministic; error ignored (launch checks anyway).
    (void)hipFuncSetAttribute(reinterpret_cast<const void*>(bin16k),
                              hipFuncAttributeMaxDynamicSharedMemorySize,
                              (int)SREC_BYTES);

    zero_cur<<<CUR_BYTES / (256 * 16), 256, 0, stream>>>((uint4*)cur);
    bin16k<<<N_ELEM / TILE, BS, SREC_BYTES, stream>>>(upd, mask, cur, rec);
    bucket_accum<<<NBUCK, BS, 0, stream>>>(rec, cur, out);
}